// Round 19
// baseline (395.109 us; speedup 1.0000x reference)
//
#include <hip/hip_runtime.h>

#define DDIM 256
#define KCODES 1024
#define MARGIN 2.0e-4f

typedef __attribute__((ext_vector_type(8))) short fragA;
typedef __attribute__((ext_vector_type(4))) float f32x4;

static __device__ __forceinline__ float4 ld4(const float* p) {
    return *reinterpret_cast<const float4*>(p);
}

static __device__ __forceinline__ ushort bf16_rne(float f) {
    unsigned bits = __float_as_uint(f);
    unsigned r = bits + 0x7FFFu + ((bits >> 16) & 1u);
    return (ushort)(r >> 16);
}

// ============ split (hi/lo bf16 planes) + row squared norm — used for C only ============
__global__ void split_sqnorm_kernel(const float* __restrict__ X, ushort* __restrict__ Xs,
                                    float* __restrict__ out, int nrows) {
    int row = blockIdx.x * 4 + (threadIdx.x >> 6);
    if (row >= nrows) return;
    int lane = threadIdx.x & 63;
    float4 v = reinterpret_cast<const float4*>(X + (size_t)row * DDIM)[lane];
    double s = (double)v.x * v.x + (double)v.y * v.y + (double)v.z * v.z + (double)v.w * v.w;
    #pragma unroll
    for (int off = 32; off > 0; off >>= 1) s += __shfl_down(s, off);
    if (lane == 0) out[row] = (float)s;

    float fv[4] = {v.x, v.y, v.z, v.w};
    ushort hb[4], lb[4];
    #pragma unroll
    for (int i = 0; i < 4; i++) {
        hb[i] = bf16_rne(fv[i]);
        float hf = __uint_as_float((unsigned)hb[i] << 16);
        lb[i] = bf16_rne(fv[i] - hf);
    }
    ushort4 hi = make_ushort4(hb[0], hb[1], hb[2], hb[3]);
    ushort4 lo = make_ushort4(lb[0], lb[1], lb[2], lb[3]);
    *reinterpret_cast<ushort4*>(Xs + (size_t)row * 512 + lane * 4) = hi;
    *reinterpret_cast<ushort4*>(Xs + (size_t)row * 512 + 256 + lane * 4) = lo;
}

// ============ MFMA argmin: fused X-split prologue + 3 independent-acc passes ============
// Block 256 thr = 4 waves, covers 64 rows. 32-code chunk = 32 KB LDS, reg-staged.
// 3 passes (hi*hi, lo*hi, hi*lo) accumulate into SEPARATE accs -> 6 independent
// MFMA dependency chains (was 2) to cover dependent-MFMA latency.
__global__ __launch_bounds__(256) void argmin_mfma_kernel(
        const float* __restrict__ X, const ushort* __restrict__ Cs,
        float* __restrict__ xsq, const float* __restrict__ csq,
        int* __restrict__ indices, int* __restrict__ flag_cnt,
        int* __restrict__ flag_list, int nrows_total) {
    __shared__ ushort clds[32 * 512];   // 32 KB

    int tid = threadIdx.x;
    int w = tid >> 6;
    int l = tid & 63;
    int lm = l & 15;
    int lg = l >> 4;
    int row0 = blockIdx.x * 64;

    // ---- fused prologue: load X row fp32, split to hi/lo, fp64 sqnorm ----
    const float* xrowf = X + (size_t)(row0 + w * 16 + lm) * DDIM;
    fragA a_hi[8], a_lo[8];
    double dsum = 0.0;
    #pragma unroll
    for (int s = 0; s < 8; s++) {
        float4 v0 = ld4(xrowf + s * 32 + lg * 8);
        float4 v1 = ld4(xrowf + s * 32 + lg * 8 + 4);
        float f[8] = {v0.x, v0.y, v0.z, v0.w, v1.x, v1.y, v1.z, v1.w};
        fragA h, lo;
        #pragma unroll
        for (int j = 0; j < 8; j++) {
            dsum += (double)f[j] * f[j];
            ushort hb = bf16_rne(f[j]);
            float hf = __uint_as_float((unsigned)hb << 16);
            ushort lb = bf16_rne(f[j] - hf);
            h[j] = (short)hb;
            lo[j] = (short)lb;
        }
        a_hi[s] = h;
        a_lo[s] = lo;
    }
    // reduce over the 4 lanes holding the same row (lanes differ in bit 4,5)
    dsum += __shfl_xor(dsum, 16);
    dsum += __shfl_xor(dsum, 32);
    float xsqf = (float)dsum;
    if (l < 16) xsq[row0 + w * 16 + l] = xsqf;   // for the exact-recheck path
    float xs_r[4];
    #pragma unroll
    for (int r = 0; r < 4; r++) xs_r[r] = __shfl(xsqf, lg * 4 + r);

    float d1[4], d2[4];
    int k1[4];
    #pragma unroll
    for (int r = 0; r < 4; r++) { d1[r] = 3.0e38f; d2[r] = 3.0e38f; k1[r] = 0; }

    for (int kc = 0; kc < KCODES; kc += 32) {
        __syncthreads();
        // stage 32 codes x 512 ushort (hi|lo), swizzled 16B chunks: p = chunk ^ (row&7)
        #pragma unroll
        for (int it = 0; it < 8; it++) {
            int c = it * 256 + tid;
            int r = c >> 6, col = c & 63;
            int p = (col & 32) | ((col & 31) ^ (r & 7));
            *reinterpret_cast<float4*>(&clds[r * 512 + p * 8]) =
                *reinterpret_cast<const float4*>(Cs + (size_t)(kc + r) * 512 + col * 8);
        }
        __syncthreads();

        f32x4 acc_hh[2], acc_lh[2], acc_hl[2];
        #pragma unroll
        for (int kt = 0; kt < 2; kt++) {
            acc_hh[kt] = (f32x4){0.f, 0.f, 0.f, 0.f};
            acc_lh[kt] = (f32x4){0.f, 0.f, 0.f, 0.f};
            acc_hl[kt] = (f32x4){0.f, 0.f, 0.f, 0.f};
        }

        #pragma unroll
        for (int s = 0; s < 8; s++) {
            #pragma unroll
            for (int kt = 0; kt < 2; kt++) {
                int kl = kt * 16 + lm;
                int chi = (4 * s + lg) ^ (kl & 7);
                fragA bhi = *reinterpret_cast<const fragA*>(&clds[kl * 512 + chi * 8]);
                fragA blo = *reinterpret_cast<const fragA*>(&clds[kl * 512 + (32 + chi) * 8]);
                acc_hh[kt] = __builtin_amdgcn_mfma_f32_16x16x32_bf16(a_hi[s], bhi, acc_hh[kt], 0, 0, 0);
                acc_lh[kt] = __builtin_amdgcn_mfma_f32_16x16x32_bf16(a_lo[s], bhi, acc_lh[kt], 0, 0, 0);
                acc_hl[kt] = __builtin_amdgcn_mfma_f32_16x16x32_bf16(a_hi[s], blo, acc_hl[kt], 0, 0, 0);
            }
        }

        #pragma unroll
        for (int kt = 0; kt < 2; kt++) {
            int k = kc + kt * 16 + lm;
            float cs = csq[k];
            #pragma unroll
            for (int r = 0; r < 4; r++) {
                float dot = (acc_hh[kt][r] + acc_lh[kt][r]) + acc_hl[kt][r];
                float dist = (xs_r[r] + cs) - 2.0f * dot;
                if (dist < d1[r] || (dist == d1[r] && k < k1[r])) {
                    d2[r] = d1[r]; d1[r] = dist; k1[r] = k;
                } else if (dist < d2[r]) {
                    d2[r] = dist;
                }
            }
        }
    }

    #pragma unroll
    for (int r = 0; r < 4; r++) {
        float bd1 = d1[r], bd2 = d2[r];
        int bk1 = k1[r];
        #pragma unroll
        for (int m = 1; m < 16; m <<= 1) {
            float od1 = __shfl_xor(bd1, m);
            int ok1 = __shfl_xor(bk1, m);
            float od2 = __shfl_xor(bd2, m);
            if (od1 < bd1 || (od1 == bd1 && ok1 < bk1)) {
                bd2 = fminf(bd1, od2); bd1 = od1; bk1 = ok1;
            } else {
                bd2 = fminf(bd2, od1);
            }
        }
        if (lm == 0) {
            int row = row0 + w * 16 + lg * 4 + r;
            indices[row] = bk1;
            if (bd2 - bd1 < MARGIN) {
                int pos = atomicAdd(flag_cnt, 1);
                if (pos < nrows_total) flag_list[pos] = row;
            }
        }
    }
}

// ============ exact fp32 recheck: (64-row x 64-code) chunks + packed atomicMin ============
#define ECH 64
#define NKCH (KCODES / ECH)

__global__ __launch_bounds__(256) void exact_chunk_kernel(
        const float* __restrict__ X, const float* __restrict__ C,
        const float* __restrict__ xsq, const float* __restrict__ csq,
        const int* __restrict__ flag_cnt, const int* __restrict__ flag_list,
        unsigned long long* __restrict__ best64, int nrows_total) {
    __shared__ float xt[64][36];
    __shared__ float ct[64][36];
    __shared__ int rowidx[64];
    __shared__ float xsql[64];

    int cnt = *flag_cnt;
    if (cnt > nrows_total) cnt = nrows_total;
    if (cnt <= 0) return;
    int ntiles = (cnt + 63) >> 6;
    int nunits = ntiles * NKCH;

    int tid = threadIdx.x;
    int tx = tid & 15;
    int ty = tid >> 4;

    for (int u = blockIdx.x; u < nunits; u += gridDim.x) {
        int t = u >> 4;
        int kc = (u & 15) * ECH;
        int base = t * 64;

        __syncthreads();
        if (tid < 64) {
            int p = base + tid;
            int row = flag_list[p < cnt ? p : base];
            rowidx[tid] = row;
            xsql[tid] = xsq[row];
        }
        __syncthreads();

        float xs[4];
        #pragma unroll
        for (int i = 0; i < 4; i++) xs[i] = xsql[i * 16 + ty];

        float acc[4][4];
        #pragma unroll
        for (int i = 0; i < 4; i++)
            #pragma unroll
            for (int j = 0; j < 4; j++) acc[i][j] = 0.0f;

        for (int dt = 0; dt < DDIM; dt += 32) {
            __syncthreads();
            #pragma unroll
            for (int it = 0; it < 2; it++) {
                int e = it * 256 + tid;
                int r = e >> 3, c4 = e & 7;
                *reinterpret_cast<float4*>(&xt[r][c4 * 4]) =
                    ld4(X + (size_t)rowidx[r] * DDIM + dt + c4 * 4);
            }
            #pragma unroll
            for (int it = 0; it < 2; it++) {
                int e = it * 256 + tid;
                int r = e >> 3, c4 = e & 7;
                *reinterpret_cast<float4*>(&ct[r][c4 * 4]) =
                    ld4(C + (size_t)(kc + r) * DDIM + dt + c4 * 4);
            }
            __syncthreads();

            for (int d4 = 0; d4 < 32; d4 += 4) {
                float4 xv[4], cv[4];
                #pragma unroll
                for (int i = 0; i < 4; i++)
                    xv[i] = *reinterpret_cast<const float4*>(&xt[i * 16 + ty][d4]);
                #pragma unroll
                for (int j = 0; j < 4; j++)
                    cv[j] = *reinterpret_cast<const float4*>(&ct[j * 16 + tx][d4]);
                #pragma unroll
                for (int i = 0; i < 4; i++)
                    #pragma unroll
                    for (int j = 0; j < 4; j++) {
                        float a = acc[i][j];
                        a += xv[i].x * cv[j].x; a += xv[i].y * cv[j].y;
                        a += xv[i].z * cv[j].z; a += xv[i].w * cv[j].w;
                        acc[i][j] = a;
                    }
            }
        }

        float cs_r[4];
        #pragma unroll
        for (int j = 0; j < 4; j++) cs_r[j] = csq[kc + j * 16 + tx];

        #pragma unroll
        for (int i = 0; i < 4; i++) {
            float bd = 3.0e38f; int bk = 0;
            #pragma unroll
            for (int j = 0; j < 4; j++) {
                int kk = kc + j * 16 + tx;
                float tt = xs[i] + cs_r[j];
                float dist = tt - 2.0f * acc[i][j];
                if (dist < bd || (dist == bd && kk < bk)) { bd = dist; bk = kk; }
            }
            #pragma unroll
            for (int m = 1; m < 16; m <<= 1) {
                float od = __shfl_xor(bd, m);
                int ok = __shfl_xor(bk, m);
                if (od < bd || (od == bd && ok < bk)) { bd = od; bk = ok; }
            }
            if (tx == 0) {
                int p = base + i * 16 + ty;
                if (p < cnt) {
                    unsigned long long pk =
                        ((unsigned long long)__float_as_uint(bd) << 32) | (unsigned)bk;
                    atomicMin(&best64[p], pk);
                }
            }
        }
    }
}

__global__ void exact_finalize_kernel(const int* __restrict__ flag_cnt,
                                      const int* __restrict__ flag_list,
                                      const unsigned long long* __restrict__ best64,
                                      int* __restrict__ indices, int nrows_total) {
    int cnt = *flag_cnt;
    if (cnt > nrows_total) cnt = nrows_total;
    for (int i = blockIdx.x * 256 + threadIdx.x; i < cnt; i += gridDim.x * 256)
        indices[flag_list[i]] = (int)(best64[i] & 0xFFFFFFFFULL);
}

// ============ counting-sort segmented sum ============
__global__ void hist_kernel(const int* __restrict__ idx, int* __restrict__ counts) {
    int i = blockIdx.x * 256 + threadIdx.x;
    atomicAdd(&counts[idx[i]], 1);
}

__global__ void prefix_kernel(const int* __restrict__ counts, int* __restrict__ offs,
                              int* __restrict__ cursor) {
    __shared__ int a[KCODES];
    int t = threadIdx.x;
    int v = counts[t];
    a[t] = v;
    __syncthreads();
    for (int s = 1; s < KCODES; s <<= 1) {
        int x = (t >= s) ? a[t - s] : 0;
        __syncthreads();
        a[t] += x;
        __syncthreads();
    }
    int excl = a[t] - v;
    offs[t] = excl;
    cursor[t] = excl;
}

__global__ void scatter_pos_kernel(const int* __restrict__ idx, int* __restrict__ cursor,
                                   int* __restrict__ sorted) {
    int i = blockIdx.x * 256 + threadIdx.x;
    int k = idx[i];
    int pos = atomicAdd(&cursor[k], 1);
    sorted[pos] = i;
}

// one block per code k: sum rows (no atomics), then fused EMA + divide
__global__ __launch_bounds__(256) void segsum_ema_kernel(
        const float* __restrict__ Z, const int* __restrict__ sorted,
        const int* __restrict__ offs, const int* __restrict__ counts,
        const float* __restrict__ ema_count, const float* __restrict__ ema_w,
        float* __restrict__ emb_new, float* __restrict__ cnt_new,
        float* __restrict__ w_new) {
    int k = blockIdx.x;
    int t = threadIdx.x;
    int start = offs[k];
    int cnt = counts[k];

    float acc = 0.f;
    int j = 0;
    for (; j + 4 <= cnt; j += 4) {
        int r0 = sorted[start + j + 0];
        int r1 = sorted[start + j + 1];
        int r2 = sorted[start + j + 2];
        int r3 = sorted[start + j + 3];
        float v0 = Z[(size_t)r0 * DDIM + t];
        float v1 = Z[(size_t)r1 * DDIM + t];
        float v2 = Z[(size_t)r2 * DDIM + t];
        float v3 = Z[(size_t)r3 * DDIM + t];
        acc += v0; acc += v1; acc += v2; acc += v3;
    }
    for (; j < cnt; j++) {
        int r = sorted[start + j];
        acc += Z[(size_t)r * DDIM + t];
    }

    const float DEC = 0.99f;
    const float OMD = (float)(1.0 - 0.99);
    float cn = __fadd_rn(__fmul_rn(DEC, ema_count[k]), __fmul_rn(OMD, (float)cnt));
    float wn = __fadd_rn(__fmul_rn(DEC, ema_w[(size_t)k * DDIM + t]), __fmul_rn(OMD, acc));
    w_new[(size_t)k * DDIM + t] = wn;
    emb_new[(size_t)k * DDIM + t] = __fdiv_rn(wn, cn);
    if (t == 0) cnt_new[k] = cn;
}

// ============ gathers ============
__global__ void gather_kernel(const float* __restrict__ emb, const float* __restrict__ emb_new,
                              const int* __restrict__ idx, float* __restrict__ zq,
                              float* __restrict__ zqb) {
    int row = blockIdx.x * 4 + (threadIdx.x >> 6);
    int lane = threadIdx.x & 63;
    int k = idx[row];
    float4 a = reinterpret_cast<const float4*>(emb + (size_t)k * DDIM)[lane];
    float4 b = reinterpret_cast<const float4*>(emb_new + (size_t)k * DDIM)[lane];
    reinterpret_cast<float4*>(zq + (size_t)row * DDIM)[lane] = a;
    reinterpret_cast<float4*>(zqb + (size_t)row * DDIM)[lane] = b;
}

extern "C" void kernel_launch(void* const* d_in, const int* in_sizes, int n_in,
                              void* d_out, int out_size, void* d_ws, size_t ws_size,
                              hipStream_t stream) {
    const float* x = (const float*)d_in[0];
    const float* z = (const float*)d_in[1];
    const float* emb = (const float*)d_in[2];
    const float* ema_count = (const float*)d_in[3];
    const float* ema_w = (const float*)d_in[4];

    const int N = in_sizes[0] / DDIM;   // 65536
    const int K = in_sizes[3];          // 1024

    float* out = (float*)d_out;
    float* zq = out;
    float* zqb = zq + (size_t)N * DDIM;
    float* emb_new = zqb + (size_t)N * DDIM;
    float* cnt_new = emb_new + (size_t)K * DDIM;
    float* w_new = cnt_new + K;

    // workspace layout (xsplit no longer needed — X handled in argmin prologue)
    char* wsb = (char*)d_ws;
    size_t off = 0;
    ushort* csplit = (ushort*)(wsb + off); off += (size_t)K * 512 * 2;      // 1 MiB
    float* xsq = (float*)(wsb + off); off += (size_t)N * 4;
    float* csq = (float*)(wsb + off); off += (size_t)K * 4;
    int* indices = (int*)(wsb + off); off += (size_t)N * 4;
    int* flag_list = (int*)(wsb + off); off += (size_t)N * 4;
    int* sorted = (int*)(wsb + off); off += (size_t)N * 4;
    int* offs = (int*)(wsb + off); off += (size_t)K * 4;
    int* counts = (int*)(wsb + off); off += (size_t)K * 4;
    int* cursor = (int*)(wsb + off); off += (size_t)K * 4;
    int* flag_cnt = (int*)(wsb + off); off += 16;
    unsigned long long* best64 = (unsigned long long*)(wsb + off); off += (size_t)N * 8;

    // zero counts + cursor + flag_cnt (contiguous); init best64 to all-ones
    hipMemsetAsync(counts, 0, (size_t)K * 4 * 2 + 16, stream);
    hipMemsetAsync(best64, 0xFF, (size_t)N * 8, stream);
    split_sqnorm_kernel<<<K / 4, 256, 0, stream>>>(emb, csplit, csq, K);
    argmin_mfma_kernel<<<N / 64, 256, 0, stream>>>(x, csplit, xsq, csq,
                                                   indices, flag_cnt, flag_list, N);
    exact_chunk_kernel<<<256, 256, 0, stream>>>(x, emb, xsq, csq,
                                                flag_cnt, flag_list, best64, N);
    exact_finalize_kernel<<<64, 256, 0, stream>>>(flag_cnt, flag_list, best64, indices, N);
    hist_kernel<<<N / 256, 256, 0, stream>>>(indices, counts);
    prefix_kernel<<<1, KCODES, 0, stream>>>(counts, offs, cursor);
    scatter_pos_kernel<<<N / 256, 256, 0, stream>>>(indices, cursor, sorted);
    segsum_ema_kernel<<<K, 256, 0, stream>>>(z, sorted, offs, counts,
                                             ema_count, ema_w,
                                             emb_new, cnt_new, w_new);
    gather_kernel<<<N / 4, 256, 0, stream>>>(emb, emb_new, indices, zq, zqb);
}

// Round 20
// 287.105 us; speedup vs baseline: 1.3762x; 1.3762x over previous
//
#include <hip/hip_runtime.h>

#define DDIM 256
#define KCODES 1024
#define MARGIN 2.0e-4f

typedef __attribute__((ext_vector_type(8))) short fragA;
typedef __attribute__((ext_vector_type(4))) float f32x4;

static __device__ __forceinline__ float4 ld4(const float* p) {
    return *reinterpret_cast<const float4*>(p);
}

static __device__ __forceinline__ ushort bf16_rne(float f) {
    unsigned bits = __float_as_uint(f);
    unsigned r = bits + 0x7FFFu + ((bits >> 16) & 1u);
    return (ushort)(r >> 16);
}

// ============ split (hi/lo bf16 planes) + row squared norm — used for C only ============
__global__ void split_sqnorm_kernel(const float* __restrict__ X, ushort* __restrict__ Xs,
                                    float* __restrict__ out, int nrows) {
    int row = blockIdx.x * 4 + (threadIdx.x >> 6);
    if (row >= nrows) return;
    int lane = threadIdx.x & 63;
    float4 v = reinterpret_cast<const float4*>(X + (size_t)row * DDIM)[lane];
    double s = (double)v.x * v.x + (double)v.y * v.y + (double)v.z * v.z + (double)v.w * v.w;
    #pragma unroll
    for (int off = 32; off > 0; off >>= 1) s += __shfl_down(s, off);
    if (lane == 0) out[row] = (float)s;

    float fv[4] = {v.x, v.y, v.z, v.w};
    ushort hb[4], lb[4];
    #pragma unroll
    for (int i = 0; i < 4; i++) {
        hb[i] = bf16_rne(fv[i]);
        float hf = __uint_as_float((unsigned)hb[i] << 16);
        lb[i] = bf16_rne(fv[i] - hf);
    }
    ushort4 hi = make_ushort4(hb[0], hb[1], hb[2], hb[3]);
    ushort4 lo = make_ushort4(lb[0], lb[1], lb[2], lb[3]);
    *reinterpret_cast<ushort4*>(Xs + (size_t)row * 512 + lane * 4) = hi;
    *reinterpret_cast<ushort4*>(Xs + (size_t)row * 512 + 256 + lane * 4) = lo;
}

// ============ MFMA argmin: fused X-split prologue + 3-pass split-bf16 main loop ============
// Block 256 thr = 4 waves, covers 64 rows. 32-code chunk = 32 KB LDS, reg-staged
// (round-11 validated staging: compiler issue-early overlap). X read fp32 directly;
// hi/lo bf16 conversion + fp64 sqnorm computed in the prologue (replaces split pass).
// NOTE: sequential accumulation into acc[kt] is intentional — the 3-independent-acc
// variant (round 19) regressed 60% (MAI hazard stalls); do not re-split.
__global__ __launch_bounds__(256) void argmin_mfma_kernel(
        const float* __restrict__ X, const ushort* __restrict__ Cs,
        float* __restrict__ xsq, const float* __restrict__ csq,
        int* __restrict__ indices, int* __restrict__ flag_cnt,
        int* __restrict__ flag_list, int nrows_total) {
    __shared__ ushort clds[32 * 512];   // 32 KB

    int tid = threadIdx.x;
    int w = tid >> 6;
    int l = tid & 63;
    int lm = l & 15;
    int lg = l >> 4;
    int row0 = blockIdx.x * 64;

    // ---- fused prologue: load X row fp32, split to hi/lo, fp64 sqnorm ----
    const float* xrowf = X + (size_t)(row0 + w * 16 + lm) * DDIM;
    fragA a_hi[8], a_lo[8];
    double dsum = 0.0;
    #pragma unroll
    for (int s = 0; s < 8; s++) {
        float4 v0 = ld4(xrowf + s * 32 + lg * 8);
        float4 v1 = ld4(xrowf + s * 32 + lg * 8 + 4);
        float f[8] = {v0.x, v0.y, v0.z, v0.w, v1.x, v1.y, v1.z, v1.w};
        fragA h, lo;
        #pragma unroll
        for (int j = 0; j < 8; j++) {
            dsum += (double)f[j] * f[j];
            ushort hb = bf16_rne(f[j]);
            float hf = __uint_as_float((unsigned)hb << 16);
            ushort lb = bf16_rne(f[j] - hf);
            h[j] = (short)hb;
            lo[j] = (short)lb;
        }
        a_hi[s] = h;
        a_lo[s] = lo;
    }
    // reduce over the 4 lanes holding the same row (lanes differ in bit 4,5)
    dsum += __shfl_xor(dsum, 16);
    dsum += __shfl_xor(dsum, 32);
    float xsqf = (float)dsum;
    if (l < 16) xsq[row0 + w * 16 + l] = xsqf;   // for the exact-recheck path
    float xs_r[4];
    #pragma unroll
    for (int r = 0; r < 4; r++) xs_r[r] = __shfl(xsqf, lg * 4 + r);

    float d1[4], d2[4];
    int k1[4];
    #pragma unroll
    for (int r = 0; r < 4; r++) { d1[r] = 3.0e38f; d2[r] = 3.0e38f; k1[r] = 0; }

    for (int kc = 0; kc < KCODES; kc += 32) {
        __syncthreads();
        // stage 32 codes x 512 ushort (hi|lo), swizzled 16B chunks: p = chunk ^ (row&7)
        #pragma unroll
        for (int it = 0; it < 8; it++) {
            int c = it * 256 + tid;
            int r = c >> 6, col = c & 63;
            int p = (col & 32) | ((col & 31) ^ (r & 7));
            *reinterpret_cast<float4*>(&clds[r * 512 + p * 8]) =
                *reinterpret_cast<const float4*>(Cs + (size_t)(kc + r) * 512 + col * 8);
        }
        __syncthreads();

        f32x4 acc[2];
        #pragma unroll
        for (int kt = 0; kt < 2; kt++) acc[kt] = (f32x4){0.f, 0.f, 0.f, 0.f};

        #pragma unroll
        for (int s = 0; s < 8; s++) {
            #pragma unroll
            for (int kt = 0; kt < 2; kt++) {
                int kl = kt * 16 + lm;
                int chi = (4 * s + lg) ^ (kl & 7);
                fragA bhi = *reinterpret_cast<const fragA*>(&clds[kl * 512 + chi * 8]);
                fragA blo = *reinterpret_cast<const fragA*>(&clds[kl * 512 + (32 + chi) * 8]);
                acc[kt] = __builtin_amdgcn_mfma_f32_16x16x32_bf16(a_hi[s], bhi, acc[kt], 0, 0, 0);
                acc[kt] = __builtin_amdgcn_mfma_f32_16x16x32_bf16(a_lo[s], bhi, acc[kt], 0, 0, 0);
                acc[kt] = __builtin_amdgcn_mfma_f32_16x16x32_bf16(a_hi[s], blo, acc[kt], 0, 0, 0);
            }
        }

        #pragma unroll
        for (int kt = 0; kt < 2; kt++) {
            int k = kc + kt * 16 + lm;
            float cs = csq[k];
            #pragma unroll
            for (int r = 0; r < 4; r++) {
                float dist = (xs_r[r] + cs) - 2.0f * acc[kt][r];
                if (dist < d1[r] || (dist == d1[r] && k < k1[r])) {
                    d2[r] = d1[r]; d1[r] = dist; k1[r] = k;
                } else if (dist < d2[r]) {
                    d2[r] = dist;
                }
            }
        }
    }

    #pragma unroll
    for (int r = 0; r < 4; r++) {
        float bd1 = d1[r], bd2 = d2[r];
        int bk1 = k1[r];
        #pragma unroll
        for (int m = 1; m < 16; m <<= 1) {
            float od1 = __shfl_xor(bd1, m);
            int ok1 = __shfl_xor(bk1, m);
            float od2 = __shfl_xor(bd2, m);
            if (od1 < bd1 || (od1 == bd1 && ok1 < bk1)) {
                bd2 = fminf(bd1, od2); bd1 = od1; bk1 = ok1;
            } else {
                bd2 = fminf(bd2, od1);
            }
        }
        if (lm == 0) {
            int row = row0 + w * 16 + lg * 4 + r;
            indices[row] = bk1;
            if (bd2 - bd1 < MARGIN) {
                int pos = atomicAdd(flag_cnt, 1);
                if (pos < nrows_total) flag_list[pos] = row;
            }
        }
    }
}

// ============ exact fp32 recheck: (64-row x 64-code) chunks + packed atomicMin ============
#define ECH 64
#define NKCH (KCODES / ECH)

__global__ __launch_bounds__(256) void exact_chunk_kernel(
        const float* __restrict__ X, const float* __restrict__ C,
        const float* __restrict__ xsq, const float* __restrict__ csq,
        const int* __restrict__ flag_cnt, const int* __restrict__ flag_list,
        unsigned long long* __restrict__ best64, int nrows_total) {
    __shared__ float xt[64][36];
    __shared__ float ct[64][36];
    __shared__ int rowidx[64];
    __shared__ float xsql[64];

    int cnt = *flag_cnt;
    if (cnt > nrows_total) cnt = nrows_total;
    if (cnt <= 0) return;
    int ntiles = (cnt + 63) >> 6;
    int nunits = ntiles * NKCH;

    int tid = threadIdx.x;
    int tx = tid & 15;
    int ty = tid >> 4;

    for (int u = blockIdx.x; u < nunits; u += gridDim.x) {
        int t = u >> 4;
        int kc = (u & 15) * ECH;
        int base = t * 64;

        __syncthreads();
        if (tid < 64) {
            int p = base + tid;
            int row = flag_list[p < cnt ? p : base];
            rowidx[tid] = row;
            xsql[tid] = xsq[row];
        }
        __syncthreads();

        float xs[4];
        #pragma unroll
        for (int i = 0; i < 4; i++) xs[i] = xsql[i * 16 + ty];

        float acc[4][4];
        #pragma unroll
        for (int i = 0; i < 4; i++)
            #pragma unroll
            for (int j = 0; j < 4; j++) acc[i][j] = 0.0f;

        for (int dt = 0; dt < DDIM; dt += 32) {
            __syncthreads();
            #pragma unroll
            for (int it = 0; it < 2; it++) {
                int e = it * 256 + tid;
                int r = e >> 3, c4 = e & 7;
                *reinterpret_cast<float4*>(&xt[r][c4 * 4]) =
                    ld4(X + (size_t)rowidx[r] * DDIM + dt + c4 * 4);
            }
            #pragma unroll
            for (int it = 0; it < 2; it++) {
                int e = it * 256 + tid;
                int r = e >> 3, c4 = e & 7;
                *reinterpret_cast<float4*>(&ct[r][c4 * 4]) =
                    ld4(C + (size_t)(kc + r) * DDIM + dt + c4 * 4);
            }
            __syncthreads();

            for (int d4 = 0; d4 < 32; d4 += 4) {
                float4 xv[4], cv[4];
                #pragma unroll
                for (int i = 0; i < 4; i++)
                    xv[i] = *reinterpret_cast<const float4*>(&xt[i * 16 + ty][d4]);
                #pragma unroll
                for (int j = 0; j < 4; j++)
                    cv[j] = *reinterpret_cast<const float4*>(&ct[j * 16 + tx][d4]);
                #pragma unroll
                for (int i = 0; i < 4; i++)
                    #pragma unroll
                    for (int j = 0; j < 4; j++) {
                        float a = acc[i][j];
                        a += xv[i].x * cv[j].x; a += xv[i].y * cv[j].y;
                        a += xv[i].z * cv[j].z; a += xv[i].w * cv[j].w;
                        acc[i][j] = a;
                    }
            }
        }

        float cs_r[4];
        #pragma unroll
        for (int j = 0; j < 4; j++) cs_r[j] = csq[kc + j * 16 + tx];

        #pragma unroll
        for (int i = 0; i < 4; i++) {
            float bd = 3.0e38f; int bk = 0;
            #pragma unroll
            for (int j = 0; j < 4; j++) {
                int kk = kc + j * 16 + tx;
                float tt = xs[i] + cs_r[j];
                float dist = tt - 2.0f * acc[i][j];
                if (dist < bd || (dist == bd && kk < bk)) { bd = dist; bk = kk; }
            }
            #pragma unroll
            for (int m = 1; m < 16; m <<= 1) {
                float od = __shfl_xor(bd, m);
                int ok = __shfl_xor(bk, m);
                if (od < bd || (od == bd && ok < bk)) { bd = od; bk = ok; }
            }
            if (tx == 0) {
                int p = base + i * 16 + ty;
                if (p < cnt) {
                    unsigned long long pk =
                        ((unsigned long long)__float_as_uint(bd) << 32) | (unsigned)bk;
                    atomicMin(&best64[p], pk);
                }
            }
        }
    }
}

__global__ void exact_finalize_kernel(const int* __restrict__ flag_cnt,
                                      const int* __restrict__ flag_list,
                                      const unsigned long long* __restrict__ best64,
                                      int* __restrict__ indices, int nrows_total) {
    int cnt = *flag_cnt;
    if (cnt > nrows_total) cnt = nrows_total;
    for (int i = blockIdx.x * 256 + threadIdx.x; i < cnt; i += gridDim.x * 256)
        indices[flag_list[i]] = (int)(best64[i] & 0xFFFFFFFFULL);
}

// ============ counting-sort segmented sum ============
__global__ void hist_kernel(const int* __restrict__ idx, int* __restrict__ counts) {
    int i = blockIdx.x * 256 + threadIdx.x;
    atomicAdd(&counts[idx[i]], 1);
}

__global__ void prefix_kernel(const int* __restrict__ counts, int* __restrict__ offs,
                              int* __restrict__ cursor) {
    __shared__ int a[KCODES];
    int t = threadIdx.x;
    int v = counts[t];
    a[t] = v;
    __syncthreads();
    for (int s = 1; s < KCODES; s <<= 1) {
        int x = (t >= s) ? a[t - s] : 0;
        __syncthreads();
        a[t] += x;
        __syncthreads();
    }
    int excl = a[t] - v;
    offs[t] = excl;
    cursor[t] = excl;
}

__global__ void scatter_pos_kernel(const int* __restrict__ idx, int* __restrict__ cursor,
                                   int* __restrict__ sorted) {
    int i = blockIdx.x * 256 + threadIdx.x;
    int k = idx[i];
    int pos = atomicAdd(&cursor[k], 1);
    sorted[pos] = i;
}

// one block per code k: sum rows (no atomics), then fused EMA + divide
__global__ __launch_bounds__(256) void segsum_ema_kernel(
        const float* __restrict__ Z, const int* __restrict__ sorted,
        const int* __restrict__ offs, const int* __restrict__ counts,
        const float* __restrict__ ema_count, const float* __restrict__ ema_w,
        float* __restrict__ emb_new, float* __restrict__ cnt_new,
        float* __restrict__ w_new) {
    int k = blockIdx.x;
    int t = threadIdx.x;
    int start = offs[k];
    int cnt = counts[k];

    float acc = 0.f;
    int j = 0;
    for (; j + 4 <= cnt; j += 4) {
        int r0 = sorted[start + j + 0];
        int r1 = sorted[start + j + 1];
        int r2 = sorted[start + j + 2];
        int r3 = sorted[start + j + 3];
        float v0 = Z[(size_t)r0 * DDIM + t];
        float v1 = Z[(size_t)r1 * DDIM + t];
        float v2 = Z[(size_t)r2 * DDIM + t];
        float v3 = Z[(size_t)r3 * DDIM + t];
        acc += v0; acc += v1; acc += v2; acc += v3;
    }
    for (; j < cnt; j++) {
        int r = sorted[start + j];
        acc += Z[(size_t)r * DDIM + t];
    }

    const float DEC = 0.99f;
    const float OMD = (float)(1.0 - 0.99);
    float cn = __fadd_rn(__fmul_rn(DEC, ema_count[k]), __fmul_rn(OMD, (float)cnt));
    float wn = __fadd_rn(__fmul_rn(DEC, ema_w[(size_t)k * DDIM + t]), __fmul_rn(OMD, acc));
    w_new[(size_t)k * DDIM + t] = wn;
    emb_new[(size_t)k * DDIM + t] = __fdiv_rn(wn, cn);
    if (t == 0) cnt_new[k] = cn;
}

// ============ gathers ============
__global__ void gather_kernel(const float* __restrict__ emb, const float* __restrict__ emb_new,
                              const int* __restrict__ idx, float* __restrict__ zq,
                              float* __restrict__ zqb) {
    int row = blockIdx.x * 4 + (threadIdx.x >> 6);
    int lane = threadIdx.x & 63;
    int k = idx[row];
    float4 a = reinterpret_cast<const float4*>(emb + (size_t)k * DDIM)[lane];
    float4 b = reinterpret_cast<const float4*>(emb_new + (size_t)k * DDIM)[lane];
    reinterpret_cast<float4*>(zq + (size_t)row * DDIM)[lane] = a;
    reinterpret_cast<float4*>(zqb + (size_t)row * DDIM)[lane] = b;
}

extern "C" void kernel_launch(void* const* d_in, const int* in_sizes, int n_in,
                              void* d_out, int out_size, void* d_ws, size_t ws_size,
                              hipStream_t stream) {
    const float* x = (const float*)d_in[0];
    const float* z = (const float*)d_in[1];
    const float* emb = (const float*)d_in[2];
    const float* ema_count = (const float*)d_in[3];
    const float* ema_w = (const float*)d_in[4];

    const int N = in_sizes[0] / DDIM;   // 65536
    const int K = in_sizes[3];          // 1024

    float* out = (float*)d_out;
    float* zq = out;
    float* zqb = zq + (size_t)N * DDIM;
    float* emb_new = zqb + (size_t)N * DDIM;
    float* cnt_new = emb_new + (size_t)K * DDIM;
    float* w_new = cnt_new + K;

    // workspace layout (xsplit no longer needed — X handled in argmin prologue)
    char* wsb = (char*)d_ws;
    size_t off = 0;
    ushort* csplit = (ushort*)(wsb + off); off += (size_t)K * 512 * 2;      // 1 MiB
    float* xsq = (float*)(wsb + off); off += (size_t)N * 4;
    float* csq = (float*)(wsb + off); off += (size_t)K * 4;
    int* indices = (int*)(wsb + off); off += (size_t)N * 4;
    int* flag_list = (int*)(wsb + off); off += (size_t)N * 4;
    int* sorted = (int*)(wsb + off); off += (size_t)N * 4;
    int* offs = (int*)(wsb + off); off += (size_t)K * 4;
    int* counts = (int*)(wsb + off); off += (size_t)K * 4;
    int* cursor = (int*)(wsb + off); off += (size_t)K * 4;
    int* flag_cnt = (int*)(wsb + off); off += 16;
    unsigned long long* best64 = (unsigned long long*)(wsb + off); off += (size_t)N * 8;

    // zero counts + cursor + flag_cnt (contiguous); init best64 to all-ones
    hipMemsetAsync(counts, 0, (size_t)K * 4 * 2 + 16, stream);
    hipMemsetAsync(best64, 0xFF, (size_t)N * 8, stream);
    split_sqnorm_kernel<<<K / 4, 256, 0, stream>>>(emb, csplit, csq, K);
    argmin_mfma_kernel<<<N / 64, 256, 0, stream>>>(x, csplit, xsq, csq,
                                                   indices, flag_cnt, flag_list, N);
    exact_chunk_kernel<<<256, 256, 0, stream>>>(x, emb, xsq, csq,
                                                flag_cnt, flag_list, best64, N);
    exact_finalize_kernel<<<64, 256, 0, stream>>>(flag_cnt, flag_list, best64, indices, N);
    hist_kernel<<<N / 256, 256, 0, stream>>>(indices, counts);
    prefix_kernel<<<1, KCODES, 0, stream>>>(counts, offs, cursor);
    scatter_pos_kernel<<<N / 256, 256, 0, stream>>>(indices, cursor, sorted);
    segsum_ema_kernel<<<K, 256, 0, stream>>>(z, sorted, offs, counts,
                                             ema_count, ema_w,
                                             emb_new, cnt_new, w_new);
    gather_kernel<<<N / 4, 256, 0, stream>>>(emb, emb_new, indices, zq, zqb);
}

// Round 21
// 273.203 us; speedup vs baseline: 1.4462x; 1.0509x over previous
//
#include <hip/hip_runtime.h>

#define DDIM 256
#define KCODES 1024
#define MARGIN 2.0e-4f

typedef __attribute__((ext_vector_type(8))) short fragA;
typedef __attribute__((ext_vector_type(4))) float f32x4;

static __device__ __forceinline__ float4 ld4(const float* p) {
    return *reinterpret_cast<const float4*>(p);
}

static __device__ __forceinline__ ushort bf16_rne(float f) {
    unsigned bits = __float_as_uint(f);
    unsigned r = bits + 0x7FFFu + ((bits >> 16) & 1u);
    return (ushort)(r >> 16);
}

// ============ split (hi/lo bf16 planes) + row squared norm — used for C only ============
__global__ void split_sqnorm_kernel(const float* __restrict__ X, ushort* __restrict__ Xs,
                                    float* __restrict__ out, int nrows) {
    int row = blockIdx.x * 4 + (threadIdx.x >> 6);
    if (row >= nrows) return;
    int lane = threadIdx.x & 63;
    float4 v = reinterpret_cast<const float4*>(X + (size_t)row * DDIM)[lane];
    double s = (double)v.x * v.x + (double)v.y * v.y + (double)v.z * v.z + (double)v.w * v.w;
    #pragma unroll
    for (int off = 32; off > 0; off >>= 1) s += __shfl_down(s, off);
    if (lane == 0) out[row] = (float)s;

    float fv[4] = {v.x, v.y, v.z, v.w};
    ushort hb[4], lb[4];
    #pragma unroll
    for (int i = 0; i < 4; i++) {
        hb[i] = bf16_rne(fv[i]);
        float hf = __uint_as_float((unsigned)hb[i] << 16);
        lb[i] = bf16_rne(fv[i] - hf);
    }
    ushort4 hi = make_ushort4(hb[0], hb[1], hb[2], hb[3]);
    ushort4 lo = make_ushort4(lb[0], lb[1], lb[2], lb[3]);
    *reinterpret_cast<ushort4*>(Xs + (size_t)row * 512 + lane * 4) = hi;
    *reinterpret_cast<ushort4*>(Xs + (size_t)row * 512 + 256 + lane * 4) = lo;
}

// ============ MFMA argmin: fused X-split prologue + 3-pass split-bf16 main loop ============
// Block 256 thr = 4 waves, covers 64 rows. 32-code chunk = 32 KB LDS, reg-staged.
// NOTE: sequential accumulation into acc[kt] is intentional — the 3-independent-acc
// variant (round 19) regressed 60% (MAI hazard stalls); do not re-split.
// Fused hist: counts[bk1]++ at index-write (preliminary; finalize fixes flagged rows).
__global__ __launch_bounds__(256) void argmin_mfma_kernel(
        const float* __restrict__ X, const ushort* __restrict__ Cs,
        float* __restrict__ xsq, const float* __restrict__ csq,
        int* __restrict__ indices, int* __restrict__ flag_cnt,
        int* __restrict__ flag_list, int* __restrict__ counts, int nrows_total) {
    __shared__ ushort clds[32 * 512];   // 32 KB

    int tid = threadIdx.x;
    int w = tid >> 6;
    int l = tid & 63;
    int lm = l & 15;
    int lg = l >> 4;
    int row0 = blockIdx.x * 64;

    // ---- fused prologue: load X row fp32, split to hi/lo, fp64 sqnorm ----
    const float* xrowf = X + (size_t)(row0 + w * 16 + lm) * DDIM;
    fragA a_hi[8], a_lo[8];
    double dsum = 0.0;
    #pragma unroll
    for (int s = 0; s < 8; s++) {
        float4 v0 = ld4(xrowf + s * 32 + lg * 8);
        float4 v1 = ld4(xrowf + s * 32 + lg * 8 + 4);
        float f[8] = {v0.x, v0.y, v0.z, v0.w, v1.x, v1.y, v1.z, v1.w};
        fragA h, lo;
        #pragma unroll
        for (int j = 0; j < 8; j++) {
            dsum += (double)f[j] * f[j];
            ushort hb = bf16_rne(f[j]);
            float hf = __uint_as_float((unsigned)hb << 16);
            ushort lb = bf16_rne(f[j] - hf);
            h[j] = (short)hb;
            lo[j] = (short)lb;
        }
        a_hi[s] = h;
        a_lo[s] = lo;
    }
    // reduce over the 4 lanes holding the same row (lanes differ in bit 4,5)
    dsum += __shfl_xor(dsum, 16);
    dsum += __shfl_xor(dsum, 32);
    float xsqf = (float)dsum;
    if (l < 16) xsq[row0 + w * 16 + l] = xsqf;   // for the exact-recheck path
    float xs_r[4];
    #pragma unroll
    for (int r = 0; r < 4; r++) xs_r[r] = __shfl(xsqf, lg * 4 + r);

    float d1[4], d2[4];
    int k1[4];
    #pragma unroll
    for (int r = 0; r < 4; r++) { d1[r] = 3.0e38f; d2[r] = 3.0e38f; k1[r] = 0; }

    for (int kc = 0; kc < KCODES; kc += 32) {
        __syncthreads();
        // stage 32 codes x 512 ushort (hi|lo), swizzled 16B chunks: p = chunk ^ (row&7)
        #pragma unroll
        for (int it = 0; it < 8; it++) {
            int c = it * 256 + tid;
            int r = c >> 6, col = c & 63;
            int p = (col & 32) | ((col & 31) ^ (r & 7));
            *reinterpret_cast<float4*>(&clds[r * 512 + p * 8]) =
                *reinterpret_cast<const float4*>(Cs + (size_t)(kc + r) * 512 + col * 8);
        }
        __syncthreads();

        f32x4 acc[2];
        #pragma unroll
        for (int kt = 0; kt < 2; kt++) acc[kt] = (f32x4){0.f, 0.f, 0.f, 0.f};

        #pragma unroll
        for (int s = 0; s < 8; s++) {
            #pragma unroll
            for (int kt = 0; kt < 2; kt++) {
                int kl = kt * 16 + lm;
                int chi = (4 * s + lg) ^ (kl & 7);
                fragA bhi = *reinterpret_cast<const fragA*>(&clds[kl * 512 + chi * 8]);
                fragA blo = *reinterpret_cast<const fragA*>(&clds[kl * 512 + (32 + chi) * 8]);
                acc[kt] = __builtin_amdgcn_mfma_f32_16x16x32_bf16(a_hi[s], bhi, acc[kt], 0, 0, 0);
                acc[kt] = __builtin_amdgcn_mfma_f32_16x16x32_bf16(a_lo[s], bhi, acc[kt], 0, 0, 0);
                acc[kt] = __builtin_amdgcn_mfma_f32_16x16x32_bf16(a_hi[s], blo, acc[kt], 0, 0, 0);
            }
        }

        #pragma unroll
        for (int kt = 0; kt < 2; kt++) {
            int k = kc + kt * 16 + lm;
            float cs = csq[k];
            #pragma unroll
            for (int r = 0; r < 4; r++) {
                float dist = (xs_r[r] + cs) - 2.0f * acc[kt][r];
                if (dist < d1[r] || (dist == d1[r] && k < k1[r])) {
                    d2[r] = d1[r]; d1[r] = dist; k1[r] = k;
                } else if (dist < d2[r]) {
                    d2[r] = dist;
                }
            }
        }
    }

    #pragma unroll
    for (int r = 0; r < 4; r++) {
        float bd1 = d1[r], bd2 = d2[r];
        int bk1 = k1[r];
        #pragma unroll
        for (int m = 1; m < 16; m <<= 1) {
            float od1 = __shfl_xor(bd1, m);
            int ok1 = __shfl_xor(bk1, m);
            float od2 = __shfl_xor(bd2, m);
            if (od1 < bd1 || (od1 == bd1 && ok1 < bk1)) {
                bd2 = fminf(bd1, od2); bd1 = od1; bk1 = ok1;
            } else {
                bd2 = fminf(bd2, od1);
            }
        }
        if (lm == 0) {
            int row = row0 + w * 16 + lg * 4 + r;
            indices[row] = bk1;
            atomicAdd(&counts[bk1], 1);          // fused hist (preliminary)
            if (bd2 - bd1 < MARGIN) {
                int pos = atomicAdd(flag_cnt, 1);
                if (pos < nrows_total) flag_list[pos] = row;
            }
        }
    }
}

// ============ exact fp32 recheck: (64-row x 64-code) chunks + packed atomicMin ============
#define ECH 64
#define NKCH (KCODES / ECH)

__global__ __launch_bounds__(256) void exact_chunk_kernel(
        const float* __restrict__ X, const float* __restrict__ C,
        const float* __restrict__ xsq, const float* __restrict__ csq,
        const int* __restrict__ flag_cnt, const int* __restrict__ flag_list,
        unsigned long long* __restrict__ best64, int nrows_total) {
    __shared__ float xt[64][36];
    __shared__ float ct[64][36];
    __shared__ int rowidx[64];
    __shared__ float xsql[64];

    int cnt = *flag_cnt;
    if (cnt > nrows_total) cnt = nrows_total;
    if (cnt <= 0) return;
    int ntiles = (cnt + 63) >> 6;
    int nunits = ntiles * NKCH;

    int tid = threadIdx.x;
    int tx = tid & 15;
    int ty = tid >> 4;

    for (int u = blockIdx.x; u < nunits; u += gridDim.x) {
        int t = u >> 4;
        int kc = (u & 15) * ECH;
        int base = t * 64;

        __syncthreads();
        if (tid < 64) {
            int p = base + tid;
            int row = flag_list[p < cnt ? p : base];
            rowidx[tid] = row;
            xsql[tid] = xsq[row];
        }
        __syncthreads();

        float xs[4];
        #pragma unroll
        for (int i = 0; i < 4; i++) xs[i] = xsql[i * 16 + ty];

        float acc[4][4];
        #pragma unroll
        for (int i = 0; i < 4; i++)
            #pragma unroll
            for (int j = 0; j < 4; j++) acc[i][j] = 0.0f;

        for (int dt = 0; dt < DDIM; dt += 32) {
            __syncthreads();
            #pragma unroll
            for (int it = 0; it < 2; it++) {
                int e = it * 256 + tid;
                int r = e >> 3, c4 = e & 7;
                *reinterpret_cast<float4*>(&xt[r][c4 * 4]) =
                    ld4(X + (size_t)rowidx[r] * DDIM + dt + c4 * 4);
            }
            #pragma unroll
            for (int it = 0; it < 2; it++) {
                int e = it * 256 + tid;
                int r = e >> 3, c4 = e & 7;
                *reinterpret_cast<float4*>(&ct[r][c4 * 4]) =
                    ld4(C + (size_t)(kc + r) * DDIM + dt + c4 * 4);
            }
            __syncthreads();

            for (int d4 = 0; d4 < 32; d4 += 4) {
                float4 xv[4], cv[4];
                #pragma unroll
                for (int i = 0; i < 4; i++)
                    xv[i] = *reinterpret_cast<const float4*>(&xt[i * 16 + ty][d4]);
                #pragma unroll
                for (int j = 0; j < 4; j++)
                    cv[j] = *reinterpret_cast<const float4*>(&ct[j * 16 + tx][d4]);
                #pragma unroll
                for (int i = 0; i < 4; i++)
                    #pragma unroll
                    for (int j = 0; j < 4; j++) {
                        float a = acc[i][j];
                        a += xv[i].x * cv[j].x; a += xv[i].y * cv[j].y;
                        a += xv[i].z * cv[j].z; a += xv[i].w * cv[j].w;
                        acc[i][j] = a;
                    }
            }
        }

        float cs_r[4];
        #pragma unroll
        for (int j = 0; j < 4; j++) cs_r[j] = csq[kc + j * 16 + tx];

        #pragma unroll
        for (int i = 0; i < 4; i++) {
            float bd = 3.0e38f; int bk = 0;
            #pragma unroll
            for (int j = 0; j < 4; j++) {
                int kk = kc + j * 16 + tx;
                float tt = xs[i] + cs_r[j];
                float dist = tt - 2.0f * acc[i][j];
                if (dist < bd || (dist == bd && kk < bk)) { bd = dist; bk = kk; }
            }
            #pragma unroll
            for (int m = 1; m < 16; m <<= 1) {
                float od = __shfl_xor(bd, m);
                int ok = __shfl_xor(bk, m);
                if (od < bd || (od == bd && ok < bk)) { bd = od; bk = ok; }
            }
            if (tx == 0) {
                int p = base + i * 16 + ty;
                if (p < cnt) {
                    unsigned long long pk =
                        ((unsigned long long)__float_as_uint(bd) << 32) | (unsigned)bk;
                    atomicMin(&best64[p], pk);
                }
            }
        }
    }
}

// finalize: write corrected index; fix the fused histogram for changed rows
__global__ void exact_finalize_kernel(const int* __restrict__ flag_cnt,
                                      const int* __restrict__ flag_list,
                                      const unsigned long long* __restrict__ best64,
                                      int* __restrict__ indices, int* __restrict__ counts,
                                      int nrows_total) {
    int cnt = *flag_cnt;
    if (cnt > nrows_total) cnt = nrows_total;
    for (int i = blockIdx.x * 256 + threadIdx.x; i < cnt; i += gridDim.x * 256) {
        int row = flag_list[i];
        int newk = (int)(best64[i] & 0xFFFFFFFFULL);
        int oldk = indices[row];
        if (newk != oldk) {
            indices[row] = newk;
            atomicAdd(&counts[oldk], -1);
            atomicAdd(&counts[newk], 1);
        }
    }
}

// ============ prefix scan over counts ============
__global__ void prefix_kernel(const int* __restrict__ counts, int* __restrict__ offs,
                              int* __restrict__ cursor) {
    __shared__ int a[KCODES];
    int t = threadIdx.x;
    int v = counts[t];
    a[t] = v;
    __syncthreads();
    for (int s = 1; s < KCODES; s <<= 1) {
        int x = (t >= s) ? a[t - s] : 0;
        __syncthreads();
        a[t] += x;
        __syncthreads();
    }
    int excl = a[t] - v;
    offs[t] = excl;
    cursor[t] = excl;
}

__global__ void scatter_pos_kernel(const int* __restrict__ idx, int* __restrict__ cursor,
                                   int* __restrict__ sorted) {
    int i = blockIdx.x * 256 + threadIdx.x;
    int k = idx[i];
    int pos = atomicAdd(&cursor[k], 1);
    sorted[pos] = i;
}

// one block per code k: sum rows (no atomics), fused EMA + divide, then write
// BOTH gathers for the bucket's rows (zq from emb, zqb from the just-computed en).
// Buckets partition [0,N) so every row is written exactly once. Bit-identical to
// the separate gather (same fp32 values, register-sourced).
__global__ __launch_bounds__(256) void segsum_ema_gather_kernel(
        const float* __restrict__ Z, const int* __restrict__ sorted,
        const int* __restrict__ offs, const int* __restrict__ counts,
        const float* __restrict__ ema_count, const float* __restrict__ ema_w,
        const float* __restrict__ emb,
        float* __restrict__ emb_new, float* __restrict__ cnt_new,
        float* __restrict__ w_new, float* __restrict__ zq, float* __restrict__ zqb) {
    int k = blockIdx.x;
    int t = threadIdx.x;     // d index
    int start = offs[k];
    int cnt = counts[k];

    float acc = 0.f;
    int j = 0;
    for (; j + 4 <= cnt; j += 4) {
        int r0 = sorted[start + j + 0];
        int r1 = sorted[start + j + 1];
        int r2 = sorted[start + j + 2];
        int r3 = sorted[start + j + 3];
        float v0 = Z[(size_t)r0 * DDIM + t];
        float v1 = Z[(size_t)r1 * DDIM + t];
        float v2 = Z[(size_t)r2 * DDIM + t];
        float v3 = Z[(size_t)r3 * DDIM + t];
        acc += v0; acc += v1; acc += v2; acc += v3;
    }
    for (; j < cnt; j++) {
        int r = sorted[start + j];
        acc += Z[(size_t)r * DDIM + t];
    }

    const float DEC = 0.99f;
    const float OMD = (float)(1.0 - 0.99);
    float cn = __fadd_rn(__fmul_rn(DEC, ema_count[k]), __fmul_rn(OMD, (float)cnt));
    float wn = __fadd_rn(__fmul_rn(DEC, ema_w[(size_t)k * DDIM + t]), __fmul_rn(OMD, acc));
    float en = __fdiv_rn(wn, cn);
    w_new[(size_t)k * DDIM + t] = wn;
    emb_new[(size_t)k * DDIM + t] = en;
    if (t == 0) cnt_new[k] = cn;

    // fused gathers: old-codebook value and new-codebook value for every bucket row
    float embk = emb[(size_t)k * DDIM + t];
    for (j = 0; j + 2 <= cnt; j += 2) {
        int r0 = sorted[start + j + 0];
        int r1 = sorted[start + j + 1];
        zq[(size_t)r0 * DDIM + t] = embk;
        zqb[(size_t)r0 * DDIM + t] = en;
        zq[(size_t)r1 * DDIM + t] = embk;
        zqb[(size_t)r1 * DDIM + t] = en;
    }
    for (; j < cnt; j++) {
        int r = sorted[start + j];
        zq[(size_t)r * DDIM + t] = embk;
        zqb[(size_t)r * DDIM + t] = en;
    }
}

extern "C" void kernel_launch(void* const* d_in, const int* in_sizes, int n_in,
                              void* d_out, int out_size, void* d_ws, size_t ws_size,
                              hipStream_t stream) {
    const float* x = (const float*)d_in[0];
    const float* z = (const float*)d_in[1];
    const float* emb = (const float*)d_in[2];
    const float* ema_count = (const float*)d_in[3];
    const float* ema_w = (const float*)d_in[4];

    const int N = in_sizes[0] / DDIM;   // 65536
    const int K = in_sizes[3];          // 1024

    float* out = (float*)d_out;
    float* zq = out;
    float* zqb = zq + (size_t)N * DDIM;
    float* emb_new = zqb + (size_t)N * DDIM;
    float* cnt_new = emb_new + (size_t)K * DDIM;
    float* w_new = cnt_new + K;

    // workspace layout
    char* wsb = (char*)d_ws;
    size_t off = 0;
    ushort* csplit = (ushort*)(wsb + off); off += (size_t)K * 512 * 2;      // 1 MiB
    float* xsq = (float*)(wsb + off); off += (size_t)N * 4;
    float* csq = (float*)(wsb + off); off += (size_t)K * 4;
    int* indices = (int*)(wsb + off); off += (size_t)N * 4;
    int* flag_list = (int*)(wsb + off); off += (size_t)N * 4;
    int* sorted = (int*)(wsb + off); off += (size_t)N * 4;
    int* offs = (int*)(wsb + off); off += (size_t)K * 4;
    int* counts = (int*)(wsb + off); off += (size_t)K * 4;
    int* cursor = (int*)(wsb + off); off += (size_t)K * 4;
    int* flag_cnt = (int*)(wsb + off); off += 16;
    unsigned long long* best64 = (unsigned long long*)(wsb + off); off += (size_t)N * 8;

    // zero counts + cursor + flag_cnt (contiguous); init best64 to all-ones
    hipMemsetAsync(counts, 0, (size_t)K * 4 * 2 + 16, stream);
    hipMemsetAsync(best64, 0xFF, (size_t)N * 8, stream);
    split_sqnorm_kernel<<<K / 4, 256, 0, stream>>>(emb, csplit, csq, K);
    argmin_mfma_kernel<<<N / 64, 256, 0, stream>>>(x, csplit, xsq, csq,
                                                   indices, flag_cnt, flag_list, counts, N);
    exact_chunk_kernel<<<256, 256, 0, stream>>>(x, emb, xsq, csq,
                                                flag_cnt, flag_list, best64, N);
    exact_finalize_kernel<<<64, 256, 0, stream>>>(flag_cnt, flag_list, best64,
                                                  indices, counts, N);
    prefix_kernel<<<1, KCODES, 0, stream>>>(counts, offs, cursor);
    scatter_pos_kernel<<<N / 256, 256, 0, stream>>>(indices, cursor, sorted);
    segsum_ema_gather_kernel<<<K, 256, 0, stream>>>(z, sorted, offs, counts,
                                                    ema_count, ema_w, emb,
                                                    emb_new, cnt_new, w_new, zq, zqb);
}

// Round 22
// 267.792 us; speedup vs baseline: 1.4754x; 1.0202x over previous
//
#include <hip/hip_runtime.h>

#define DDIM 256
#define KCODES 1024
#define MARGIN 2.0e-4f

typedef __attribute__((ext_vector_type(8))) short fragA;
typedef __attribute__((ext_vector_type(4))) float f32x4;

static __device__ __forceinline__ float4 ld4(const float* p) {
    return *reinterpret_cast<const float4*>(p);
}

static __device__ __forceinline__ ushort bf16_rne(float f) {
    unsigned bits = __float_as_uint(f);
    unsigned r = bits + 0x7FFFu + ((bits >> 16) & 1u);
    return (ushort)(r >> 16);
}

// ============ split (hi/lo bf16 planes) + row squared norm — used for C only ============
__global__ void split_sqnorm_kernel(const float* __restrict__ X, ushort* __restrict__ Xs,
                                    float* __restrict__ out, int nrows) {
    int row = blockIdx.x * 4 + (threadIdx.x >> 6);
    if (row >= nrows) return;
    int lane = threadIdx.x & 63;
    float4 v = reinterpret_cast<const float4*>(X + (size_t)row * DDIM)[lane];
    double s = (double)v.x * v.x + (double)v.y * v.y + (double)v.z * v.z + (double)v.w * v.w;
    #pragma unroll
    for (int off = 32; off > 0; off >>= 1) s += __shfl_down(s, off);
    if (lane == 0) out[row] = (float)s;

    float fv[4] = {v.x, v.y, v.z, v.w};
    ushort hb[4], lb[4];
    #pragma unroll
    for (int i = 0; i < 4; i++) {
        hb[i] = bf16_rne(fv[i]);
        float hf = __uint_as_float((unsigned)hb[i] << 16);
        lb[i] = bf16_rne(fv[i] - hf);
    }
    ushort4 hi = make_ushort4(hb[0], hb[1], hb[2], hb[3]);
    ushort4 lo = make_ushort4(lb[0], lb[1], lb[2], lb[3]);
    *reinterpret_cast<ushort4*>(Xs + (size_t)row * 512 + lane * 4) = hi;
    *reinterpret_cast<ushort4*>(Xs + (size_t)row * 512 + 256 + lane * 4) = lo;
}

// ============ MFMA argmin: fused X-split prologue + 3-pass split-bf16 main loop ============
// Block 256 thr = 4 waves, covers 64 rows. 32-code chunk = 32 KB LDS, reg-staged.
// NOTE: sequential accumulation into acc[kt] is intentional — the 3-independent-acc
// variant (round 19) regressed 60% (MAI hazard stalls); do not re-split.
// Fused hist via LDS-local histogram (flushed once per block; finalize fixes flagged rows).
__global__ __launch_bounds__(256) void argmin_mfma_kernel(
        const float* __restrict__ X, const ushort* __restrict__ Cs,
        float* __restrict__ xsq, const float* __restrict__ csq,
        int* __restrict__ indices, int* __restrict__ flag_cnt,
        int* __restrict__ flag_list, int* __restrict__ counts, int nrows_total) {
    __shared__ ushort clds[32 * 512];   // 32 KB
    __shared__ int hist[KCODES];        // 4 KB LDS-local histogram

    int tid = threadIdx.x;
    int w = tid >> 6;
    int l = tid & 63;
    int lm = l & 15;
    int lg = l >> 4;
    int row0 = blockIdx.x * 64;

    #pragma unroll
    for (int i = 0; i < 4; i++) hist[tid + i * 256] = 0;

    // ---- fused prologue: load X row fp32, split to hi/lo, fp64 sqnorm ----
    const float* xrowf = X + (size_t)(row0 + w * 16 + lm) * DDIM;
    fragA a_hi[8], a_lo[8];
    double dsum = 0.0;
    #pragma unroll
    for (int s = 0; s < 8; s++) {
        float4 v0 = ld4(xrowf + s * 32 + lg * 8);
        float4 v1 = ld4(xrowf + s * 32 + lg * 8 + 4);
        float f[8] = {v0.x, v0.y, v0.z, v0.w, v1.x, v1.y, v1.z, v1.w};
        fragA h, lo;
        #pragma unroll
        for (int j = 0; j < 8; j++) {
            dsum += (double)f[j] * f[j];
            ushort hb = bf16_rne(f[j]);
            float hf = __uint_as_float((unsigned)hb << 16);
            ushort lb = bf16_rne(f[j] - hf);
            h[j] = (short)hb;
            lo[j] = (short)lb;
        }
        a_hi[s] = h;
        a_lo[s] = lo;
    }
    // reduce over the 4 lanes holding the same row (lanes differ in bit 4,5)
    dsum += __shfl_xor(dsum, 16);
    dsum += __shfl_xor(dsum, 32);
    float xsqf = (float)dsum;
    if (l < 16) xsq[row0 + w * 16 + l] = xsqf;   // for the exact-recheck path
    float xs_r[4];
    #pragma unroll
    for (int r = 0; r < 4; r++) xs_r[r] = __shfl(xsqf, lg * 4 + r);

    float d1[4], d2[4];
    int k1[4];
    #pragma unroll
    for (int r = 0; r < 4; r++) { d1[r] = 3.0e38f; d2[r] = 3.0e38f; k1[r] = 0; }

    for (int kc = 0; kc < KCODES; kc += 32) {
        __syncthreads();
        // stage 32 codes x 512 ushort (hi|lo), swizzled 16B chunks: p = chunk ^ (row&7)
        #pragma unroll
        for (int it = 0; it < 8; it++) {
            int c = it * 256 + tid;
            int r = c >> 6, col = c & 63;
            int p = (col & 32) | ((col & 31) ^ (r & 7));
            *reinterpret_cast<float4*>(&clds[r * 512 + p * 8]) =
                *reinterpret_cast<const float4*>(Cs + (size_t)(kc + r) * 512 + col * 8);
        }
        __syncthreads();

        f32x4 acc[2];
        #pragma unroll
        for (int kt = 0; kt < 2; kt++) acc[kt] = (f32x4){0.f, 0.f, 0.f, 0.f};

        #pragma unroll
        for (int s = 0; s < 8; s++) {
            #pragma unroll
            for (int kt = 0; kt < 2; kt++) {
                int kl = kt * 16 + lm;
                int chi = (4 * s + lg) ^ (kl & 7);
                fragA bhi = *reinterpret_cast<const fragA*>(&clds[kl * 512 + chi * 8]);
                fragA blo = *reinterpret_cast<const fragA*>(&clds[kl * 512 + (32 + chi) * 8]);
                acc[kt] = __builtin_amdgcn_mfma_f32_16x16x32_bf16(a_hi[s], bhi, acc[kt], 0, 0, 0);
                acc[kt] = __builtin_amdgcn_mfma_f32_16x16x32_bf16(a_lo[s], bhi, acc[kt], 0, 0, 0);
                acc[kt] = __builtin_amdgcn_mfma_f32_16x16x32_bf16(a_hi[s], blo, acc[kt], 0, 0, 0);
            }
        }

        #pragma unroll
        for (int kt = 0; kt < 2; kt++) {
            int k = kc + kt * 16 + lm;
            float cs = csq[k];
            #pragma unroll
            for (int r = 0; r < 4; r++) {
                float dist = (xs_r[r] + cs) - 2.0f * acc[kt][r];
                if (dist < d1[r] || (dist == d1[r] && k < k1[r])) {
                    d2[r] = d1[r]; d1[r] = dist; k1[r] = k;
                } else if (dist < d2[r]) {
                    d2[r] = dist;
                }
            }
        }
    }

    #pragma unroll
    for (int r = 0; r < 4; r++) {
        float bd1 = d1[r], bd2 = d2[r];
        int bk1 = k1[r];
        #pragma unroll
        for (int m = 1; m < 16; m <<= 1) {
            float od1 = __shfl_xor(bd1, m);
            int ok1 = __shfl_xor(bk1, m);
            float od2 = __shfl_xor(bd2, m);
            if (od1 < bd1 || (od1 == bd1 && ok1 < bk1)) {
                bd2 = fminf(bd1, od2); bd1 = od1; bk1 = ok1;
            } else {
                bd2 = fminf(bd2, od1);
            }
        }
        if (lm == 0) {
            int row = row0 + w * 16 + lg * 4 + r;
            indices[row] = bk1;
            atomicAdd(&hist[bk1], 1);            // LDS-local hist
            if (bd2 - bd1 < MARGIN) {
                int pos = atomicAdd(flag_cnt, 1);
                if (pos < nrows_total) flag_list[pos] = row;
            }
        }
    }

    __syncthreads();
    #pragma unroll
    for (int i = 0; i < 4; i++) {
        int v = hist[tid + i * 256];
        if (v) atomicAdd(&counts[tid + i * 256], v);
    }
}

// ============ exact fp32 recheck: (64-row x 32-code) chunks + packed atomicMin ============
#define ECH 32
#define NKCH (KCODES / ECH)   // 32 chunks

__global__ __launch_bounds__(256) void exact_chunk_kernel(
        const float* __restrict__ X, const float* __restrict__ C,
        const float* __restrict__ xsq, const float* __restrict__ csq,
        const int* __restrict__ flag_cnt, const int* __restrict__ flag_list,
        unsigned long long* __restrict__ best64, int nrows_total) {
    __shared__ float xt[64][36];
    __shared__ float ct[ECH][36];
    __shared__ int rowidx[64];
    __shared__ float xsql[64];

    int cnt = *flag_cnt;
    if (cnt > nrows_total) cnt = nrows_total;
    if (cnt <= 0) return;
    int ntiles = (cnt + 63) >> 6;
    int nunits = ntiles * NKCH;

    int tid = threadIdx.x;
    int tx = tid & 15;
    int ty = tid >> 4;

    for (int u = blockIdx.x; u < nunits; u += gridDim.x) {
        int t = u >> 5;               // row tile  (u / NKCH)
        int kc = (u & 31) * ECH;      // code chunk base
        int base = t * 64;

        __syncthreads();
        if (tid < 64) {
            int p = base + tid;
            int row = flag_list[p < cnt ? p : base];
            rowidx[tid] = row;
            xsql[tid] = xsq[row];
        }
        __syncthreads();

        float xs[4];
        #pragma unroll
        for (int i = 0; i < 4; i++) xs[i] = xsql[i * 16 + ty];

        float acc[4][2];
        #pragma unroll
        for (int i = 0; i < 4; i++)
            #pragma unroll
            for (int j = 0; j < 2; j++) acc[i][j] = 0.0f;

        for (int dt = 0; dt < DDIM; dt += 32) {
            __syncthreads();
            #pragma unroll
            for (int it = 0; it < 2; it++) {
                int e = it * 256 + tid;
                int r = e >> 3, c4 = e & 7;
                *reinterpret_cast<float4*>(&xt[r][c4 * 4]) =
                    ld4(X + (size_t)rowidx[r] * DDIM + dt + c4 * 4);
            }
            {
                int e = tid;                 // 32 rows x 8 float4 = 256
                int r = e >> 3, c4 = e & 7;
                *reinterpret_cast<float4*>(&ct[r][c4 * 4]) =
                    ld4(C + (size_t)(kc + r) * DDIM + dt + c4 * 4);
            }
            __syncthreads();

            for (int d4 = 0; d4 < 32; d4 += 4) {
                float4 xv[4], cv[2];
                #pragma unroll
                for (int i = 0; i < 4; i++)
                    xv[i] = *reinterpret_cast<const float4*>(&xt[i * 16 + ty][d4]);
                #pragma unroll
                for (int j = 0; j < 2; j++)
                    cv[j] = *reinterpret_cast<const float4*>(&ct[j * 16 + tx][d4]);
                #pragma unroll
                for (int i = 0; i < 4; i++)
                    #pragma unroll
                    for (int j = 0; j < 2; j++) {
                        float a = acc[i][j];
                        a += xv[i].x * cv[j].x; a += xv[i].y * cv[j].y;
                        a += xv[i].z * cv[j].z; a += xv[i].w * cv[j].w;
                        acc[i][j] = a;
                    }
            }
        }

        float cs_r[2];
        #pragma unroll
        for (int j = 0; j < 2; j++) cs_r[j] = csq[kc + j * 16 + tx];

        #pragma unroll
        for (int i = 0; i < 4; i++) {
            float bd = 3.0e38f; int bk = 0;
            #pragma unroll
            for (int j = 0; j < 2; j++) {
                int kk = kc + j * 16 + tx;
                float tt = xs[i] + cs_r[j];
                float dist = tt - 2.0f * acc[i][j];
                if (dist < bd || (dist == bd && kk < bk)) { bd = dist; bk = kk; }
            }
            #pragma unroll
            for (int m = 1; m < 16; m <<= 1) {
                float od = __shfl_xor(bd, m);
                int ok = __shfl_xor(bk, m);
                if (od < bd || (od == bd && ok < bk)) { bd = od; bk = ok; }
            }
            if (tx == 0) {
                int p = base + i * 16 + ty;
                if (p < cnt) {
                    unsigned long long pk =
                        ((unsigned long long)__float_as_uint(bd) << 32) | (unsigned)bk;
                    atomicMin(&best64[p], pk);
                }
            }
        }
    }
}

// ============ prefix scan over counts, with fused finalize prologue ============
// Single block of KCODES threads: (1) apply exact-recheck corrections to indices
// and counts, (2) fence, (3) exclusive scan of counts -> offs/cursor.
__global__ void prefix_kernel(const int* __restrict__ flag_cnt,
                              const int* __restrict__ flag_list,
                              const unsigned long long* __restrict__ best64,
                              int* __restrict__ indices,
                              int* __restrict__ counts, int* __restrict__ offs,
                              int* __restrict__ cursor, int nrows_total) {
    int t = threadIdx.x;

    // ---- fused finalize: fix flagged rows + histogram ----
    int cnt = *flag_cnt;
    if (cnt > nrows_total) cnt = nrows_total;
    for (int i = t; i < cnt; i += KCODES) {
        int row = flag_list[i];
        int newk = (int)(best64[i] & 0xFFFFFFFFULL);
        int oldk = indices[row];
        if (newk != oldk) {
            indices[row] = newk;
            atomicAdd(&counts[oldk], -1);
            atomicAdd(&counts[newk], 1);
        }
    }
    __threadfence();
    __syncthreads();

    __shared__ int a[KCODES];
    int v = counts[t];
    a[t] = v;
    __syncthreads();
    for (int s = 1; s < KCODES; s <<= 1) {
        int x = (t >= s) ? a[t - s] : 0;
        __syncthreads();
        a[t] += x;
        __syncthreads();
    }
    int excl = a[t] - v;
    offs[t] = excl;
    cursor[t] = excl;
}

__global__ void scatter_pos_kernel(const int* __restrict__ idx, int* __restrict__ cursor,
                                   int* __restrict__ sorted) {
    int i = blockIdx.x * 256 + threadIdx.x;
    int k = idx[i];
    int pos = atomicAdd(&cursor[k], 1);
    sorted[pos] = i;
}

// one block per code k: sum rows (no atomics), fused EMA + divide, then write
// BOTH gathers for the bucket's rows (zq from emb, zqb from the just-computed en).
__global__ __launch_bounds__(256) void segsum_ema_gather_kernel(
        const float* __restrict__ Z, const int* __restrict__ sorted,
        const int* __restrict__ offs, const int* __restrict__ counts,
        const float* __restrict__ ema_count, const float* __restrict__ ema_w,
        const float* __restrict__ emb,
        float* __restrict__ emb_new, float* __restrict__ cnt_new,
        float* __restrict__ w_new, float* __restrict__ zq, float* __restrict__ zqb) {
    int k = blockIdx.x;
    int t = threadIdx.x;     // d index
    int start = offs[k];
    int cnt = counts[k];

    float acc = 0.f;
    int j = 0;
    for (; j + 4 <= cnt; j += 4) {
        int r0 = sorted[start + j + 0];
        int r1 = sorted[start + j + 1];
        int r2 = sorted[start + j + 2];
        int r3 = sorted[start + j + 3];
        float v0 = Z[(size_t)r0 * DDIM + t];
        float v1 = Z[(size_t)r1 * DDIM + t];
        float v2 = Z[(size_t)r2 * DDIM + t];
        float v3 = Z[(size_t)r3 * DDIM + t];
        acc += v0; acc += v1; acc += v2; acc += v3;
    }
    for (; j < cnt; j++) {
        int r = sorted[start + j];
        acc += Z[(size_t)r * DDIM + t];
    }

    const float DEC = 0.99f;
    const float OMD = (float)(1.0 - 0.99);
    float cn = __fadd_rn(__fmul_rn(DEC, ema_count[k]), __fmul_rn(OMD, (float)cnt));
    float wn = __fadd_rn(__fmul_rn(DEC, ema_w[(size_t)k * DDIM + t]), __fmul_rn(OMD, acc));
    float en = __fdiv_rn(wn, cn);
    w_new[(size_t)k * DDIM + t] = wn;
    emb_new[(size_t)k * DDIM + t] = en;
    if (t == 0) cnt_new[k] = cn;

    // fused gathers: old-codebook value and new-codebook value for every bucket row
    float embk = emb[(size_t)k * DDIM + t];
    for (j = 0; j + 2 <= cnt; j += 2) {
        int r0 = sorted[start + j + 0];
        int r1 = sorted[start + j + 1];
        zq[(size_t)r0 * DDIM + t] = embk;
        zqb[(size_t)r0 * DDIM + t] = en;
        zq[(size_t)r1 * DDIM + t] = embk;
        zqb[(size_t)r1 * DDIM + t] = en;
    }
    for (; j < cnt; j++) {
        int r = sorted[start + j];
        zq[(size_t)r * DDIM + t] = embk;
        zqb[(size_t)r * DDIM + t] = en;
    }
}

extern "C" void kernel_launch(void* const* d_in, const int* in_sizes, int n_in,
                              void* d_out, int out_size, void* d_ws, size_t ws_size,
                              hipStream_t stream) {
    const float* x = (const float*)d_in[0];
    const float* z = (const float*)d_in[1];
    const float* emb = (const float*)d_in[2];
    const float* ema_count = (const float*)d_in[3];
    const float* ema_w = (const float*)d_in[4];

    const int N = in_sizes[0] / DDIM;   // 65536
    const int K = in_sizes[3];          // 1024

    float* out = (float*)d_out;
    float* zq = out;
    float* zqb = zq + (size_t)N * DDIM;
    float* emb_new = zqb + (size_t)N * DDIM;
    float* cnt_new = emb_new + (size_t)K * DDIM;
    float* w_new = cnt_new + K;

    // workspace layout
    char* wsb = (char*)d_ws;
    size_t off = 0;
    ushort* csplit = (ushort*)(wsb + off); off += (size_t)K * 512 * 2;      // 1 MiB
    float* xsq = (float*)(wsb + off); off += (size_t)N * 4;
    float* csq = (float*)(wsb + off); off += (size_t)K * 4;
    int* indices = (int*)(wsb + off); off += (size_t)N * 4;
    int* flag_list = (int*)(wsb + off); off += (size_t)N * 4;
    int* sorted = (int*)(wsb + off); off += (size_t)N * 4;
    int* offs = (int*)(wsb + off); off += (size_t)K * 4;
    int* counts = (int*)(wsb + off); off += (size_t)K * 4;
    int* cursor = (int*)(wsb + off); off += (size_t)K * 4;
    int* flag_cnt = (int*)(wsb + off); off += 16;
    unsigned long long* best64 = (unsigned long long*)(wsb + off); off += (size_t)N * 8;

    // zero counts + cursor + flag_cnt (contiguous); init best64 to all-ones
    hipMemsetAsync(counts, 0, (size_t)K * 4 * 2 + 16, stream);
    hipMemsetAsync(best64, 0xFF, (size_t)N * 8, stream);
    split_sqnorm_kernel<<<K / 4, 256, 0, stream>>>(emb, csplit, csq, K);
    argmin_mfma_kernel<<<N / 64, 256, 0, stream>>>(x, csplit, xsq, csq,
                                                   indices, flag_cnt, flag_list, counts, N);
    exact_chunk_kernel<<<512, 256, 0, stream>>>(x, emb, xsq, csq,
                                                flag_cnt, flag_list, best64, N);
    prefix_kernel<<<1, KCODES, 0, stream>>>(flag_cnt, flag_list, best64, indices,
                                            counts, offs, cursor, N);
    scatter_pos_kernel<<<N / 256, 256, 0, stream>>>(indices, cursor, sorted);
    segsum_ema_gather_kernel<<<K, 256, 0, stream>>>(z, sorted, offs, counts,
                                                    ema_count, ema_w, emb,
                                                    emb_new, cnt_new, w_new, zq, zqb);
}

// Round 23
// 262.597 us; speedup vs baseline: 1.5046x; 1.0198x over previous
//
#include <hip/hip_runtime.h>

#define DDIM 256
#define KCODES 1024
#define MARGIN 2.0e-4f

typedef __attribute__((ext_vector_type(8))) short fragA;
typedef __attribute__((ext_vector_type(4))) float f32x4;

static __device__ __forceinline__ float4 ld4(const float* p) {
    return *reinterpret_cast<const float4*>(p);
}

static __device__ __forceinline__ ushort bf16_rne(float f) {
    unsigned bits = __float_as_uint(f);
    unsigned r = bits + 0x7FFFu + ((bits >> 16) & 1u);
    return (ushort)(r >> 16);
}

// ============ split (hi/lo bf16) + row sqnorm for C, fused workspace zeroing ============
// 256 blocks x 256 thr = 65536 threads; gid < 2052 also zero counts/cursor/flag_cnt.
__global__ void split_sqnorm_kernel(const float* __restrict__ X, ushort* __restrict__ Xs,
                                    float* __restrict__ out, int nrows,
                                    int* __restrict__ counts, int* __restrict__ cursor,
                                    int* __restrict__ flag_cnt) {
    int gid = blockIdx.x * 256 + threadIdx.x;
    if (gid < KCODES) counts[gid] = 0;
    else if (gid < 2 * KCODES) cursor[gid - KCODES] = 0;
    else if (gid < 2 * KCODES + 4) flag_cnt[gid - 2 * KCODES] = 0;

    int row = blockIdx.x * 4 + (threadIdx.x >> 6);
    if (row >= nrows) return;
    int lane = threadIdx.x & 63;
    float4 v = reinterpret_cast<const float4*>(X + (size_t)row * DDIM)[lane];
    double s = (double)v.x * v.x + (double)v.y * v.y + (double)v.z * v.z + (double)v.w * v.w;
    #pragma unroll
    for (int off = 32; off > 0; off >>= 1) s += __shfl_down(s, off);
    if (lane == 0) out[row] = (float)s;

    float fv[4] = {v.x, v.y, v.z, v.w};
    ushort hb[4], lb[4];
    #pragma unroll
    for (int i = 0; i < 4; i++) {
        hb[i] = bf16_rne(fv[i]);
        float hf = __uint_as_float((unsigned)hb[i] << 16);
        lb[i] = bf16_rne(fv[i] - hf);
    }
    ushort4 hi = make_ushort4(hb[0], hb[1], hb[2], hb[3]);
    ushort4 lo = make_ushort4(lb[0], lb[1], lb[2], lb[3]);
    *reinterpret_cast<ushort4*>(Xs + (size_t)row * 512 + lane * 4) = hi;
    *reinterpret_cast<ushort4*>(Xs + (size_t)row * 512 + 256 + lane * 4) = lo;
}

// ============ MFMA argmin: fused X-split prologue + 3-pass split-bf16 main loop ============
// Block 256 thr = 4 waves, covers 64 rows. 32-code chunk = 32 KB LDS, reg-staged.
// NOTE: sequential accumulation into acc[kt] is intentional — the 3-independent-acc
// variant (round 19) regressed 60% (MAI hazard stalls); do not re-split.
// Fused hist via LDS-local histogram; best64 lazily initialized at flag time.
__global__ __launch_bounds__(256) void argmin_mfma_kernel(
        const float* __restrict__ X, const ushort* __restrict__ Cs,
        float* __restrict__ xsq, const float* __restrict__ csq,
        int* __restrict__ indices, int* __restrict__ flag_cnt,
        int* __restrict__ flag_list, int* __restrict__ counts,
        unsigned long long* __restrict__ best64, int nrows_total) {
    __shared__ ushort clds[32 * 512];   // 32 KB
    __shared__ int hist[KCODES];        // 4 KB LDS-local histogram

    int tid = threadIdx.x;
    int w = tid >> 6;
    int l = tid & 63;
    int lm = l & 15;
    int lg = l >> 4;
    int row0 = blockIdx.x * 64;

    #pragma unroll
    for (int i = 0; i < 4; i++) hist[tid + i * 256] = 0;

    // ---- fused prologue: load X row fp32, split to hi/lo, fp64 sqnorm ----
    const float* xrowf = X + (size_t)(row0 + w * 16 + lm) * DDIM;
    fragA a_hi[8], a_lo[8];
    double dsum = 0.0;
    #pragma unroll
    for (int s = 0; s < 8; s++) {
        float4 v0 = ld4(xrowf + s * 32 + lg * 8);
        float4 v1 = ld4(xrowf + s * 32 + lg * 8 + 4);
        float f[8] = {v0.x, v0.y, v0.z, v0.w, v1.x, v1.y, v1.z, v1.w};
        fragA h, lo;
        #pragma unroll
        for (int j = 0; j < 8; j++) {
            dsum += (double)f[j] * f[j];
            ushort hb = bf16_rne(f[j]);
            float hf = __uint_as_float((unsigned)hb << 16);
            ushort lb = bf16_rne(f[j] - hf);
            h[j] = (short)hb;
            lo[j] = (short)lb;
        }
        a_hi[s] = h;
        a_lo[s] = lo;
    }
    // reduce over the 4 lanes holding the same row (lanes differ in bit 4,5)
    dsum += __shfl_xor(dsum, 16);
    dsum += __shfl_xor(dsum, 32);
    float xsqf = (float)dsum;
    if (l < 16) xsq[row0 + w * 16 + l] = xsqf;   // for the exact-recheck path
    float xs_r[4];
    #pragma unroll
    for (int r = 0; r < 4; r++) xs_r[r] = __shfl(xsqf, lg * 4 + r);

    float d1[4], d2[4];
    int k1[4];
    #pragma unroll
    for (int r = 0; r < 4; r++) { d1[r] = 3.0e38f; d2[r] = 3.0e38f; k1[r] = 0; }

    for (int kc = 0; kc < KCODES; kc += 32) {
        __syncthreads();
        // stage 32 codes x 512 ushort (hi|lo), swizzled 16B chunks: p = chunk ^ (row&7)
        #pragma unroll
        for (int it = 0; it < 8; it++) {
            int c = it * 256 + tid;
            int r = c >> 6, col = c & 63;
            int p = (col & 32) | ((col & 31) ^ (r & 7));
            *reinterpret_cast<float4*>(&clds[r * 512 + p * 8]) =
                *reinterpret_cast<const float4*>(Cs + (size_t)(kc + r) * 512 + col * 8);
        }
        __syncthreads();

        f32x4 acc[2];
        #pragma unroll
        for (int kt = 0; kt < 2; kt++) acc[kt] = (f32x4){0.f, 0.f, 0.f, 0.f};

        #pragma unroll
        for (int s = 0; s < 8; s++) {
            #pragma unroll
            for (int kt = 0; kt < 2; kt++) {
                int kl = kt * 16 + lm;
                int chi = (4 * s + lg) ^ (kl & 7);
                fragA bhi = *reinterpret_cast<const fragA*>(&clds[kl * 512 + chi * 8]);
                fragA blo = *reinterpret_cast<const fragA*>(&clds[kl * 512 + (32 + chi) * 8]);
                acc[kt] = __builtin_amdgcn_mfma_f32_16x16x32_bf16(a_hi[s], bhi, acc[kt], 0, 0, 0);
                acc[kt] = __builtin_amdgcn_mfma_f32_16x16x32_bf16(a_lo[s], bhi, acc[kt], 0, 0, 0);
                acc[kt] = __builtin_amdgcn_mfma_f32_16x16x32_bf16(a_hi[s], blo, acc[kt], 0, 0, 0);
            }
        }

        #pragma unroll
        for (int kt = 0; kt < 2; kt++) {
            int k = kc + kt * 16 + lm;
            float cs = csq[k];
            #pragma unroll
            for (int r = 0; r < 4; r++) {
                float dist = (xs_r[r] + cs) - 2.0f * acc[kt][r];
                if (dist < d1[r] || (dist == d1[r] && k < k1[r])) {
                    d2[r] = d1[r]; d1[r] = dist; k1[r] = k;
                } else if (dist < d2[r]) {
                    d2[r] = dist;
                }
            }
        }
    }

    #pragma unroll
    for (int r = 0; r < 4; r++) {
        float bd1 = d1[r], bd2 = d2[r];
        int bk1 = k1[r];
        #pragma unroll
        for (int m = 1; m < 16; m <<= 1) {
            float od1 = __shfl_xor(bd1, m);
            int ok1 = __shfl_xor(bk1, m);
            float od2 = __shfl_xor(bd2, m);
            if (od1 < bd1 || (od1 == bd1 && ok1 < bk1)) {
                bd2 = fminf(bd1, od2); bd1 = od1; bk1 = ok1;
            } else {
                bd2 = fminf(bd2, od1);
            }
        }
        if (lm == 0) {
            int row = row0 + w * 16 + lg * 4 + r;
            indices[row] = bk1;
            atomicAdd(&hist[bk1], 1);            // LDS-local hist
            if (bd2 - bd1 < MARGIN) {
                int pos = atomicAdd(flag_cnt, 1);
                if (pos < nrows_total) {
                    flag_list[pos] = row;
                    best64[pos] = 0xFFFFFFFFFFFFFFFFULL;   // lazy init (replaces memset)
                }
            }
        }
    }

    __syncthreads();
    #pragma unroll
    for (int i = 0; i < 4; i++) {
        int v = hist[tid + i * 256];
        if (v) atomicAdd(&counts[tid + i * 256], v);
    }
}

// ============ exact fp32 recheck: (64-row x 32-code) chunks + packed atomicMin ============
#define ECH 32
#define NKCH (KCODES / ECH)   // 32 chunks

__global__ __launch_bounds__(256) void exact_chunk_kernel(
        const float* __restrict__ X, const float* __restrict__ C,
        const float* __restrict__ xsq, const float* __restrict__ csq,
        const int* __restrict__ flag_cnt, const int* __restrict__ flag_list,
        unsigned long long* __restrict__ best64, int nrows_total) {
    __shared__ float xt[64][36];
    __shared__ float ct[ECH][36];
    __shared__ int rowidx[64];
    __shared__ float xsql[64];

    int cnt = *flag_cnt;
    if (cnt > nrows_total) cnt = nrows_total;
    if (cnt <= 0) return;
    int ntiles = (cnt + 63) >> 6;
    int nunits = ntiles * NKCH;

    int tid = threadIdx.x;
    int tx = tid & 15;
    int ty = tid >> 4;

    for (int u = blockIdx.x; u < nunits; u += gridDim.x) {
        int t = u >> 5;               // row tile  (u / NKCH)
        int kc = (u & 31) * ECH;      // code chunk base
        int base = t * 64;

        __syncthreads();
        if (tid < 64) {
            int p = base + tid;
            int row = flag_list[p < cnt ? p : base];
            rowidx[tid] = row;
            xsql[tid] = xsq[row];
        }
        __syncthreads();

        float xs[4];
        #pragma unroll
        for (int i = 0; i < 4; i++) xs[i] = xsql[i * 16 + ty];

        float acc[4][2];
        #pragma unroll
        for (int i = 0; i < 4; i++)
            #pragma unroll
            for (int j = 0; j < 2; j++) acc[i][j] = 0.0f;

        for (int dt = 0; dt < DDIM; dt += 32) {
            __syncthreads();
            #pragma unroll
            for (int it = 0; it < 2; it++) {
                int e = it * 256 + tid;
                int r = e >> 3, c4 = e & 7;
                *reinterpret_cast<float4*>(&xt[r][c4 * 4]) =
                    ld4(X + (size_t)rowidx[r] * DDIM + dt + c4 * 4);
            }
            {
                int e = tid;                 // 32 rows x 8 float4 = 256
                int r = e >> 3, c4 = e & 7;
                *reinterpret_cast<float4*>(&ct[r][c4 * 4]) =
                    ld4(C + (size_t)(kc + r) * DDIM + dt + c4 * 4);
            }
            __syncthreads();

            for (int d4 = 0; d4 < 32; d4 += 4) {
                float4 xv[4], cv[2];
                #pragma unroll
                for (int i = 0; i < 4; i++)
                    xv[i] = *reinterpret_cast<const float4*>(&xt[i * 16 + ty][d4]);
                #pragma unroll
                for (int j = 0; j < 2; j++)
                    cv[j] = *reinterpret_cast<const float4*>(&ct[j * 16 + tx][d4]);
                #pragma unroll
                for (int i = 0; i < 4; i++)
                    #pragma unroll
                    for (int j = 0; j < 2; j++) {
                        float a = acc[i][j];
                        a += xv[i].x * cv[j].x; a += xv[i].y * cv[j].y;
                        a += xv[i].z * cv[j].z; a += xv[i].w * cv[j].w;
                        acc[i][j] = a;
                    }
            }
        }

        float cs_r[2];
        #pragma unroll
        for (int j = 0; j < 2; j++) cs_r[j] = csq[kc + j * 16 + tx];

        #pragma unroll
        for (int i = 0; i < 4; i++) {
            float bd = 3.0e38f; int bk = 0;
            #pragma unroll
            for (int j = 0; j < 2; j++) {
                int kk = kc + j * 16 + tx;
                float tt = xs[i] + cs_r[j];
                float dist = tt - 2.0f * acc[i][j];
                if (dist < bd || (dist == bd && kk < bk)) { bd = dist; bk = kk; }
            }
            #pragma unroll
            for (int m = 1; m < 16; m <<= 1) {
                float od = __shfl_xor(bd, m);
                int ok = __shfl_xor(bk, m);
                if (od < bd || (od == bd && ok < bk)) { bd = od; bk = ok; }
            }
            if (tx == 0) {
                int p = base + i * 16 + ty;
                if (p < cnt) {
                    unsigned long long pk =
                        ((unsigned long long)__float_as_uint(bd) << 32) | (unsigned)bk;
                    atomicMin(&best64[p], pk);
                }
            }
        }
    }
}

// ============ prefix scan over counts, with fused finalize prologue ============
__global__ void prefix_kernel(const int* __restrict__ flag_cnt,
                              const int* __restrict__ flag_list,
                              const unsigned long long* __restrict__ best64,
                              int* __restrict__ indices,
                              int* __restrict__ counts, int* __restrict__ offs,
                              int* __restrict__ cursor, int nrows_total) {
    int t = threadIdx.x;

    // ---- fused finalize: fix flagged rows + histogram ----
    int cnt = *flag_cnt;
    if (cnt > nrows_total) cnt = nrows_total;
    for (int i = t; i < cnt; i += KCODES) {
        int row = flag_list[i];
        int newk = (int)(best64[i] & 0xFFFFFFFFULL);
        int oldk = indices[row];
        if (newk != oldk) {
            indices[row] = newk;
            atomicAdd(&counts[oldk], -1);
            atomicAdd(&counts[newk], 1);
        }
    }
    __threadfence();
    __syncthreads();

    __shared__ int a[KCODES];
    int v = counts[t];
    a[t] = v;
    __syncthreads();
    for (int s = 1; s < KCODES; s <<= 1) {
        int x = (t >= s) ? a[t - s] : 0;
        __syncthreads();
        a[t] += x;
        __syncthreads();
    }
    int excl = a[t] - v;
    offs[t] = excl;
    cursor[t] = excl;
}

__global__ void scatter_pos_kernel(const int* __restrict__ idx, int* __restrict__ cursor,
                                   int* __restrict__ sorted) {
    int i = blockIdx.x * 256 + threadIdx.x;
    int k = idx[i];
    int pos = atomicAdd(&cursor[k], 1);
    sorted[pos] = i;
}

// one block per code k: sum rows (no atomics), fused EMA + divide, then write
// BOTH gathers for the bucket's rows (zq from emb, zqb from the just-computed en).
__global__ __launch_bounds__(256) void segsum_ema_gather_kernel(
        const float* __restrict__ Z, const int* __restrict__ sorted,
        const int* __restrict__ offs, const int* __restrict__ counts,
        const float* __restrict__ ema_count, const float* __restrict__ ema_w,
        const float* __restrict__ emb,
        float* __restrict__ emb_new, float* __restrict__ cnt_new,
        float* __restrict__ w_new, float* __restrict__ zq, float* __restrict__ zqb) {
    int k = blockIdx.x;
    int t = threadIdx.x;     // d index
    int start = offs[k];
    int cnt = counts[k];

    float acc = 0.f;
    int j = 0;
    for (; j + 4 <= cnt; j += 4) {
        int r0 = sorted[start + j + 0];
        int r1 = sorted[start + j + 1];
        int r2 = sorted[start + j + 2];
        int r3 = sorted[start + j + 3];
        float v0 = Z[(size_t)r0 * DDIM + t];
        float v1 = Z[(size_t)r1 * DDIM + t];
        float v2 = Z[(size_t)r2 * DDIM + t];
        float v3 = Z[(size_t)r3 * DDIM + t];
        acc += v0; acc += v1; acc += v2; acc += v3;
    }
    for (; j < cnt; j++) {
        int r = sorted[start + j];
        acc += Z[(size_t)r * DDIM + t];
    }

    const float DEC = 0.99f;
    const float OMD = (float)(1.0 - 0.99);
    float cn = __fadd_rn(__fmul_rn(DEC, ema_count[k]), __fmul_rn(OMD, (float)cnt));
    float wn = __fadd_rn(__fmul_rn(DEC, ema_w[(size_t)k * DDIM + t]), __fmul_rn(OMD, acc));
    float en = __fdiv_rn(wn, cn);
    w_new[(size_t)k * DDIM + t] = wn;
    emb_new[(size_t)k * DDIM + t] = en;
    if (t == 0) cnt_new[k] = cn;

    // fused gathers: old-codebook value and new-codebook value for every bucket row
    float embk = emb[(size_t)k * DDIM + t];
    for (j = 0; j + 2 <= cnt; j += 2) {
        int r0 = sorted[start + j + 0];
        int r1 = sorted[start + j + 1];
        zq[(size_t)r0 * DDIM + t] = embk;
        zqb[(size_t)r0 * DDIM + t] = en;
        zq[(size_t)r1 * DDIM + t] = embk;
        zqb[(size_t)r1 * DDIM + t] = en;
    }
    for (; j < cnt; j++) {
        int r = sorted[start + j];
        zq[(size_t)r * DDIM + t] = embk;
        zqb[(size_t)r * DDIM + t] = en;
    }
}

extern "C" void kernel_launch(void* const* d_in, const int* in_sizes, int n_in,
                              void* d_out, int out_size, void* d_ws, size_t ws_size,
                              hipStream_t stream) {
    const float* x = (const float*)d_in[0];
    const float* z = (const float*)d_in[1];
    const float* emb = (const float*)d_in[2];
    const float* ema_count = (const float*)d_in[3];
    const float* ema_w = (const float*)d_in[4];

    const int N = in_sizes[0] / DDIM;   // 65536
    const int K = in_sizes[3];          // 1024

    float* out = (float*)d_out;
    float* zq = out;
    float* zqb = zq + (size_t)N * DDIM;
    float* emb_new = zqb + (size_t)N * DDIM;
    float* cnt_new = emb_new + (size_t)K * DDIM;
    float* w_new = cnt_new + K;

    // workspace layout
    char* wsb = (char*)d_ws;
    size_t off = 0;
    ushort* csplit = (ushort*)(wsb + off); off += (size_t)K * 512 * 2;      // 1 MiB
    float* xsq = (float*)(wsb + off); off += (size_t)N * 4;
    float* csq = (float*)(wsb + off); off += (size_t)K * 4;
    int* indices = (int*)(wsb + off); off += (size_t)N * 4;
    int* flag_list = (int*)(wsb + off); off += (size_t)N * 4;
    int* sorted = (int*)(wsb + off); off += (size_t)N * 4;
    int* offs = (int*)(wsb + off); off += (size_t)K * 4;
    int* counts = (int*)(wsb + off); off += (size_t)K * 4;
    int* cursor = (int*)(wsb + off); off += (size_t)K * 4;
    int* flag_cnt = (int*)(wsb + off); off += 16;
    unsigned long long* best64 = (unsigned long long*)(wsb + off); off += (size_t)N * 8;

    // NOTE: no memsets — counts/cursor/flag_cnt zeroed in split_sqnorm_kernel
    // (runs first, same stream); best64 entries lazily initialized by argmin.
    split_sqnorm_kernel<<<256, 256, 0, stream>>>(emb, csplit, csq, K,
                                                 counts, cursor, flag_cnt);
    argmin_mfma_kernel<<<N / 64, 256, 0, stream>>>(x, csplit, xsq, csq,
                                                   indices, flag_cnt, flag_list,
                                                   counts, best64, N);
    exact_chunk_kernel<<<512, 256, 0, stream>>>(x, emb, xsq, csq,
                                                flag_cnt, flag_list, best64, N);
    prefix_kernel<<<1, KCODES, 0, stream>>>(flag_cnt, flag_list, best64, indices,
                                            counts, offs, cursor, N);
    scatter_pos_kernel<<<N / 256, 256, 0, stream>>>(indices, cursor, sorted);
    segsum_ema_gather_kernel<<<K, 256, 0, stream>>>(z, sorted, offs, counts,
                                                    ema_count, ema_w, emb,
                                                    emb_new, cnt_new, w_new, zq, zqb);
}